// Round 4
// baseline (6627.562 us; speedup 1.0000x reference)
//
#include <hip/hip_runtime.h>

// Problem constants (reference: B=2, T=2048, C=1024, V=8192, L=2, H=16, d=64)
#define BB 2
#define TT 2048
#define CC 1024
#define VV 8192
#define LL 2
#define HH 16
#define DD 64
#define MM (BB * TT) // 4096 rows

// R3 post-mortem: NaN persists with zero d_ws usage and triple-audited math.
// Remaining suspect: the float inputs may be FP32 on device (per the reference
// dtype rule), not bf16. Reading fp32 as bf16 guarantees NaN patterns from the
// low mantissa halves. This round probes the encoding at runtime (1-block
// kernel, flag in d_ws[0]) and every input-touching kernel branches on it.
// Activations we own are always bf16. Output dtype follows the flag.
//
// Scratch plan (unchanged from R3, valid in both modes):
//   d_out: [0,8M) h | [8,16M) q (ctx aliases) | [16,24M) k | [24,32M) v (bf16)
//          — dead before the logits GEMM overwrites d_out.
//   embed_w buffer (>=16 MiB both modes; consumed by embed at step 0):
//          [0,8M) h copy (bf16) | byte 12M: nll fp32 (16 KB)
//   d_ws:  [0,4) dtype flag.
using u16 = unsigned short;

__device__ __forceinline__ float bf2f(u16 u) {
    union { unsigned int i; float f; } x;
    x.i = ((unsigned int)u) << 16;
    return x.f;
}
__device__ __forceinline__ u16 f2bf(float f) {
    union { float f; unsigned int i; } x;
    x.f = f;
    unsigned int r = x.i + 0x7fffu + ((x.i >> 16) & 1u); // round-to-nearest-even
    return (u16)(r >> 16);
}

// ---------- 0. dtype probe ----------
// bf16 N(0,0.02) data: exponent field <= ~123 everywhere -> count == 0.
// fp32 data read as u16: even indices are random mantissa halves -> ~50% have
// exponent >= 125 -> count ~2000 of 4096. Threshold 64.
__global__ __launch_bounds__(256) void probe_kernel(const u16* __restrict__ w,
                                                    int* __restrict__ flag) {
    __shared__ int cnt;
    if (threadIdx.x == 0) cnt = 0;
    __syncthreads();
    int c = 0;
    for (int i = threadIdx.x; i < 4096; i += 256) {
        const u16 u = w[2 * i];
        const int e = (u >> 7) & 0xff;
        if (e >= 125) ++c;
    }
    atomicAdd(&cnt, c);
    __syncthreads();
    if (threadIdx.x == 0) *flag = (cnt > 64) ? 1 : 0;
}

// ---------- 1. embedding + positional -> bf16 h ----------
__global__ __launch_bounds__(256) void embed_kernel(const int* __restrict__ x,
                                                    const void* __restrict__ ew,
                                                    const void* __restrict__ pos,
                                                    u16* __restrict__ h,
                                                    const int* __restrict__ flagp) {
    const int f = *flagp;
    const int i = blockIdx.x;        // token row 0..MM-1
    const int t = i & (TT - 1);      // position within sequence
    const int row = x[i];
    const int c = threadIdx.x * 4;
    float4 e, p;
    if (f) {
        e = *(const float4*)((const float*)ew + (size_t)row * CC + c);
        p = *(const float4*)((const float*)pos + (size_t)t * CC + c);
    } else {
        ushort4 eu = *(const ushort4*)((const u16*)ew + (size_t)row * CC + c);
        ushort4 pu = *(const ushort4*)((const u16*)pos + (size_t)t * CC + c);
        e = make_float4(bf2f(eu.x), bf2f(eu.y), bf2f(eu.z), bf2f(eu.w));
        p = make_float4(bf2f(pu.x), bf2f(pu.y), bf2f(pu.z), bf2f(pu.w));
    }
    ushort4 o;
    o.x = f2bf(e.x + p.x); o.y = f2bf(e.y + p.y);
    o.z = f2bf(e.z + p.z); o.w = f2bf(e.w + p.w);
    *(ushort4*)&h[(size_t)i * CC + c] = o;
}

// ---------- 2. GEMM: out[m,n] = sum_k A[m,k]*W[n,k] (+bias[n]) (+res[m,n]) ----------
// A bf16 [M,K] (ours). W/bias: dtype per flag, element offsets passed in.
// res: bf16 or null (ours). out: bf16 unless (outFlagged && flag) -> fp32.
// 128x128 tile, BK=16, 256 threads, 8x8 micro-tile, fp32 FMA.
__global__ __launch_bounds__(256) void gemm_nt(const u16* __restrict__ A,
                                               const void* __restrict__ W, size_t wOff,
                                               void* __restrict__ outP,
                                               const void* __restrict__ bias, size_t bOff,
                                               const u16* __restrict__ res,
                                               int M, int N, int K, int outFlagged,
                                               const int* __restrict__ flagp) {
    const int f = *flagp;
    __shared__ float As[16][128];
    __shared__ float Bs[16][128];
    const int tid = threadIdx.x;
    const int tx = tid & 15;   // 16 col-groups of 8
    const int ty = tid >> 4;   // 16 row-groups of 8
    const int m0 = blockIdx.y * 128, n0 = blockIdx.x * 128;

    const int ar = tid >> 1;          // 0..127 (row within tile)
    const int ak = (tid & 1) * 8;     // k offset 0,8

    float acc[8][8] = {};

    for (int kt = 0; kt < K; kt += 16) {
        uint4 a4 = *(const uint4*)&A[(size_t)(m0 + ar) * K + kt + ak];
        float wv[8];
        if (f) {
            const float* Wf = (const float*)W + wOff;
            *(float4*)&wv[0] = *(const float4*)&Wf[(size_t)(n0 + ar) * K + kt + ak];
            *(float4*)&wv[4] = *(const float4*)&Wf[(size_t)(n0 + ar) * K + kt + ak + 4];
        } else {
            const u16* Wb = (const u16*)W + wOff;
            uint4 w4 = *(const uint4*)&Wb[(size_t)(n0 + ar) * K + kt + ak];
            wv[0] = bf2f((u16)(w4.x & 0xffffu)); wv[1] = bf2f((u16)(w4.x >> 16));
            wv[2] = bf2f((u16)(w4.y & 0xffffu)); wv[3] = bf2f((u16)(w4.y >> 16));
            wv[4] = bf2f((u16)(w4.z & 0xffffu)); wv[5] = bf2f((u16)(w4.z >> 16));
            wv[6] = bf2f((u16)(w4.w & 0xffffu)); wv[7] = bf2f((u16)(w4.w >> 16));
        }
        As[ak + 0][ar] = bf2f((u16)(a4.x & 0xffffu));
        As[ak + 1][ar] = bf2f((u16)(a4.x >> 16));
        As[ak + 2][ar] = bf2f((u16)(a4.y & 0xffffu));
        As[ak + 3][ar] = bf2f((u16)(a4.y >> 16));
        As[ak + 4][ar] = bf2f((u16)(a4.z & 0xffffu));
        As[ak + 5][ar] = bf2f((u16)(a4.z >> 16));
        As[ak + 6][ar] = bf2f((u16)(a4.w & 0xffffu));
        As[ak + 7][ar] = bf2f((u16)(a4.w >> 16));
        Bs[ak + 0][ar] = wv[0]; Bs[ak + 1][ar] = wv[1];
        Bs[ak + 2][ar] = wv[2]; Bs[ak + 3][ar] = wv[3];
        Bs[ak + 4][ar] = wv[4]; Bs[ak + 5][ar] = wv[5];
        Bs[ak + 6][ar] = wv[6]; Bs[ak + 7][ar] = wv[7];
        __syncthreads();
#pragma unroll
        for (int kk = 0; kk < 16; ++kk) {
            float av[8], bv[8];
            *(float4*)&av[0] = *(const float4*)&As[kk][ty * 8];
            *(float4*)&av[4] = *(const float4*)&As[kk][ty * 8 + 4];
            *(float4*)&bv[0] = *(const float4*)&Bs[kk][tx * 8];
            *(float4*)&bv[4] = *(const float4*)&Bs[kk][tx * 8 + 4];
#pragma unroll
            for (int i = 0; i < 8; ++i)
#pragma unroll
                for (int j = 0; j < 8; ++j)
                    acc[i][j] += av[i] * bv[j];
        }
        __syncthreads();
    }

#pragma unroll
    for (int i = 0; i < 8; ++i) {
        const int m = m0 + ty * 8 + i;
#pragma unroll
        for (int j = 0; j < 8; j += 4) {
            const int n = n0 + tx * 8 + j;
            float4 vv = make_float4(acc[i][j], acc[i][j + 1], acc[i][j + 2], acc[i][j + 3]);
            if (bias) {
                if (f) {
                    float4 bb = *(const float4*)((const float*)bias + bOff + n);
                    vv.x += bb.x; vv.y += bb.y; vv.z += bb.z; vv.w += bb.w;
                } else {
                    ushort4 bb = *(const ushort4*)((const u16*)bias + bOff + n);
                    vv.x += bf2f(bb.x); vv.y += bf2f(bb.y);
                    vv.z += bf2f(bb.z); vv.w += bf2f(bb.w);
                }
            }
            if (res) {
                ushort4 rr = *(const ushort4*)&res[(size_t)m * N + n];
                vv.x += bf2f(rr.x); vv.y += bf2f(rr.y);
                vv.z += bf2f(rr.z); vv.w += bf2f(rr.w);
            }
            if (outFlagged && f) {
                *(float4*)((float*)outP + (size_t)m * N + n) = vv;
            } else {
                ushort4 ob;
                ob.x = f2bf(vv.x); ob.y = f2bf(vv.y);
                ob.z = f2bf(vv.z); ob.w = f2bf(vv.w);
                *(ushort4*)((u16*)outP + (size_t)m * N + n) = ob;
            }
        }
    }
}

// ---------- 3. flash attention (fp32 math, bf16 storage — our buffers only) ----------
__global__ __launch_bounds__(64) void flash_attn(const u16* __restrict__ q,
                                                 const u16* __restrict__ k,
                                                 const u16* __restrict__ v,
                                                 u16* __restrict__ ctx) {
    const int bh = blockIdx.x;          // 0..B*H-1
    const int b = bh >> 4;              // /HH
    const int hd = bh & 15;             // %HH
    const int qb = blockIdx.y * 64;
    const int lane = threadIdx.x;
    const int qrow = qb + lane;
    const float scale = 0.125f;         // 1/sqrt(64)

    __shared__ float Ks[32][64];
    __shared__ float Vs[32][64];

    const u16* qp = q + ((size_t)(b * TT + qrow)) * CC + hd * DD;
    float qr[64];
#pragma unroll
    for (int j = 0; j < 64; j += 4) {
        ushort4 t4 = *(const ushort4*)&qp[j];
        qr[j] = bf2f(t4.x); qr[j + 1] = bf2f(t4.y);
        qr[j + 2] = bf2f(t4.z); qr[j + 3] = bf2f(t4.w);
    }
    float acc[64] = {};
    float mx = -1e30f, l = 0.f;

    for (int kb = 0; kb < qb + 64; kb += 32) {
#pragma unroll
        for (int it = 0; it < 8; ++it) {
            const int cidx = it * 64 + lane;        // 0..511
            const int row = cidx >> 4;              // 0..31
            const int c4 = (cidx & 15) * 4;         // 0..60
            const size_t g = ((size_t)(b * TT + kb + row)) * CC + hd * DD + c4;
            ushort4 kk4 = *(const ushort4*)&k[g];
            ushort4 vv4 = *(const ushort4*)&v[g];
            Ks[row][c4 + 0] = bf2f(kk4.x); Ks[row][c4 + 1] = bf2f(kk4.y);
            Ks[row][c4 + 2] = bf2f(kk4.z); Ks[row][c4 + 3] = bf2f(kk4.w);
            Vs[row][c4 + 0] = bf2f(vv4.x); Vs[row][c4 + 1] = bf2f(vv4.y);
            Vs[row][c4 + 2] = bf2f(vv4.z); Vs[row][c4 + 3] = bf2f(vv4.w);
        }
        __syncthreads();

        float s[32];
#pragma unroll
        for (int kk = 0; kk < 32; ++kk) {
            float p0 = 0.f, p1 = 0.f, p2 = 0.f, p3 = 0.f;
#pragma unroll
            for (int j = 0; j < 64; j += 4) {
                p0 += qr[j]     * Ks[kk][j];
                p1 += qr[j + 1] * Ks[kk][j + 1];
                p2 += qr[j + 2] * Ks[kk][j + 2];
                p3 += qr[j + 3] * Ks[kk][j + 3];
            }
            float sv = ((p0 + p1) + (p2 + p3)) * scale;
            s[kk] = (kb + kk <= qrow) ? sv : -1e30f;  // causal mask
        }
        float bm = s[0];
#pragma unroll
        for (int kk = 1; kk < 32; ++kk) bm = fmaxf(bm, s[kk]);
        const float mnew = fmaxf(mx, bm);
        const float corr = __expf(mx - mnew);
        l *= corr;
#pragma unroll
        for (int j = 0; j < 64; ++j) acc[j] *= corr;
#pragma unroll
        for (int kk = 0; kk < 32; ++kk) {
            const float p = __expf(s[kk] - mnew);
            l += p;
#pragma unroll
            for (int j = 0; j < 64; j += 4) {
                float4 vv = *(const float4*)&Vs[kk][j];   // broadcast read
                acc[j]     += p * vv.x;
                acc[j + 1] += p * vv.y;
                acc[j + 2] += p * vv.z;
                acc[j + 3] += p * vv.w;
            }
        }
        mx = mnew;
        __syncthreads();
    }

    const float inv = 1.0f / l;
    u16* cp = ctx + ((size_t)(b * TT + qrow)) * CC + hd * DD;
#pragma unroll
    for (int j = 0; j < 64; j += 4) {
        ushort4 o;
        o.x = f2bf(acc[j] * inv); o.y = f2bf(acc[j + 1] * inv);
        o.z = f2bf(acc[j + 2] * inv); o.w = f2bf(acc[j + 3] * inv);
        *(ushort4*)&cp[j] = o;
    }
}

// ---------- 4. d2d copy (h -> scratch), 16B per thread ----------
__global__ __launch_bounds__(256) void copy16_kernel(const uint4* __restrict__ src,
                                                     uint4* __restrict__ dst) {
    const size_t i = (size_t)blockIdx.x * 256 + threadIdx.x;
    dst[i] = src[i];
}

// ---------- 5. loss: per-row logsumexp + NLL ----------
__global__ __launch_bounds__(256) void loss_row(const void* __restrict__ logits,
                                                const int* __restrict__ target,
                                                float* __restrict__ nll,
                                                const int* __restrict__ flagp) {
    const int f = *flagp;
    const int r = blockIdx.x;
    __shared__ float red[4];
    const float* lpf = (const float*)logits + (size_t)r * VV;
    const u16*   lpb = (const u16*)logits + (size_t)r * VV;

    float lmax = -1e30f;
    if (f) { for (int i = threadIdx.x; i < VV; i += 256) lmax = fmaxf(lmax, lpf[i]); }
    else   { for (int i = threadIdx.x; i < VV; i += 256) lmax = fmaxf(lmax, bf2f(lpb[i])); }
#pragma unroll
    for (int off = 32; off > 0; off >>= 1) lmax = fmaxf(lmax, __shfl_down(lmax, off, 64));
    const int wid = threadIdx.x >> 6, lid = threadIdx.x & 63;
    if (lid == 0) red[wid] = lmax;
    __syncthreads();
    lmax = fmaxf(fmaxf(red[0], red[1]), fmaxf(red[2], red[3]));

    float sum = 0.f;
    if (f) { for (int i = threadIdx.x; i < VV; i += 256) sum += __expf(lpf[i] - lmax); }
    else   { for (int i = threadIdx.x; i < VV; i += 256) sum += __expf(bf2f(lpb[i]) - lmax); }
#pragma unroll
    for (int off = 32; off > 0; off >>= 1) sum += __shfl_down(sum, off, 64);
    __syncthreads();
    if (lid == 0) red[wid] = sum;
    __syncthreads();
    if (threadIdx.x == 0) {
        const float s = red[0] + red[1] + red[2] + red[3];
        const float tl = f ? lpf[target[r]] : bf2f(lpb[target[r]]);
        nll[r] = lmax + __logf(s) - tl;   // = -(log_softmax at target)
    }
}

__global__ __launch_bounds__(256) void loss_final(const float* __restrict__ nll,
                                                  void* __restrict__ out,
                                                  const int* __restrict__ flagp) {
    __shared__ float red[4];
    float s = 0.f;
    for (int i = threadIdx.x; i < MM; i += 256) s += nll[i];
#pragma unroll
    for (int off = 32; off > 0; off >>= 1) s += __shfl_down(s, off, 64);
    if ((threadIdx.x & 63) == 0) red[threadIdx.x >> 6] = s;
    __syncthreads();
    if (threadIdx.x == 0) {
        const float t = (red[0] + red[1] + red[2] + red[3]) / (float)MM;
        if (*flagp) ((float*)out)[(size_t)MM * VV] = t;
        else        ((u16*)out)[(size_t)MM * VV] = f2bf(t);
    }
}

// ---------- launch ----------
extern "C" void kernel_launch(void* const* d_in, const int* in_sizes, int n_in,
                              void* d_out, int out_size, void* d_ws, size_t ws_size,
                              hipStream_t stream) {
    const int* x      = (const int*)d_in[0];
    const int* target = (const int*)d_in[1];
    const void* ew  = d_in[2];
    const void* pos = d_in[3];
    const void* Wq  = d_in[4];
    const void* bq  = d_in[5];
    const void* Wk  = d_in[6];
    const void* bk  = d_in[7];
    const void* Wv  = d_in[8];
    const void* bv  = d_in[9];
    const void* Wo  = d_in[10];
    const void* bo  = d_in[11];
    const void* Wu  = d_in[12];

    int* flagp = (int*)d_ws;   // 4 bytes of workspace: dtype flag

    // bf16 scratch inside d_out (dead until logits GEMM; >=64 MiB both modes):
    u16* outw = (u16*)d_out;
    u16* hB  = outw;
    u16* qB  = outw + (size_t)1 * MM * CC;
    u16* kB  = outw + (size_t)2 * MM * CC;
    u16* vB  = outw + (size_t)3 * MM * CC;
    u16* ctx = qB;  // flash block writes exactly the (row, head-slice) it read
    // Scratch inside the consumed embed_w buffer (>=16 MiB both modes):
    u16* hScr  = (u16*)ew;                                   // [0, 8M) bytes
    float* nll = (float*)((char*)ew + 12u * 1024 * 1024);    // [12M, 12M+16K)

    probe_kernel<<<1, 256, 0, stream>>>((const u16*)Wu, flagp);
    embed_kernel<<<MM, 256, 0, stream>>>(x, ew, pos, hB, flagp);  // last read of ew

    const dim3 gP(CC / 128, MM / 128);   // projection GEMMs: 8 x 32 blocks
    for (int l = 0; l < LL; ++l) {
        const size_t wOff = (size_t)l * CC * CC, bOff = (size_t)l * CC;
        gemm_nt<<<gP, 256, 0, stream>>>(hB, Wq, wOff, qB, bq, bOff, nullptr, MM, CC, CC, 0, flagp);
        gemm_nt<<<gP, 256, 0, stream>>>(hB, Wk, wOff, kB, bk, bOff, nullptr, MM, CC, CC, 0, flagp);
        gemm_nt<<<gP, 256, 0, stream>>>(hB, Wv, wOff, vB, bv, bOff, nullptr, MM, CC, CC, 0, flagp);
        flash_attn<<<dim3(BB * HH, TT / 64), 64, 0, stream>>>(qB, kB, vB, ctx);
        // out-proj + residual, in-place into hB (res read/write at identical (m,n))
        gemm_nt<<<gP, 256, 0, stream>>>(ctx, Wo, wOff, hB, bo, bOff, hB, MM, CC, CC, 0, flagp);
    }

    // move h out of d_out, then logits GEMM overwrites d_out (dtype per flag)
    copy16_kernel<<<(MM * CC * 2 / 16) / 256, 256, 0, stream>>>((const uint4*)hB, (uint4*)hScr);
    gemm_nt<<<dim3(VV / 128, MM / 128), 256, 0, stream>>>(hScr, Wu, 0, d_out,
                                                          nullptr, 0, nullptr, MM, VV, CC, 1, flagp);
    loss_row<<<MM, 256, 0, stream>>>(d_out, target, nll, flagp);
    loss_final<<<1, 256, 0, stream>>>(nll, d_out, flagp);
}

// Round 5
// 5456.560 us; speedup vs baseline: 1.2146x; 1.2146x over previous
//
#include <hip/hip_runtime.h>

// Problem constants (reference: B=2, T=2048, C=1024, V=8192, L=2, H=16, d=64)
#define BB 2
#define TT 2048
#define CC 1024
#define VV 8192
#define LL 2
#define HH 16
#define DD 64
#define MM (BB * TT) // 4096 rows

// R4: correctness established (inputs are FP32 on device; probe flag=1).
// This round: split-K flash attention. Old kernel was 1 wave/block, occupancy
// 6.3%, VALUBusy 13.6% -> pure latency exposure (4.4 of 6.6 ms total).
// New: 4 waves/block share one 64-query tile; wave w does 16-row KV tiles
// t%4==w (each wave exactly qt+1 tiles -> lockstep barriers legal); per-wave
// 8KB LDS staging; online-softmax merge through padded LDS at the end.
using u16 = unsigned short;

__device__ __forceinline__ float bf2f(u16 u) {
    union { unsigned int i; float f; } x;
    x.i = ((unsigned int)u) << 16;
    return x.f;
}
__device__ __forceinline__ u16 f2bf(float f) {
    union { float f; unsigned int i; } x;
    x.f = f;
    unsigned int r = x.i + 0x7fffu + ((x.i >> 16) & 1u); // round-to-nearest-even
    return (u16)(r >> 16);
}

// ---------- 0. dtype probe (kept from R4 — resolved fp32-vs-bf16 at runtime) ----------
__global__ __launch_bounds__(256) void probe_kernel(const u16* __restrict__ w,
                                                    int* __restrict__ flag) {
    __shared__ int cnt;
    if (threadIdx.x == 0) cnt = 0;
    __syncthreads();
    int c = 0;
    for (int i = threadIdx.x; i < 4096; i += 256) {
        const u16 u = w[2 * i];
        const int e = (u >> 7) & 0xff;
        if (e >= 125) ++c;
    }
    atomicAdd(&cnt, c);
    __syncthreads();
    if (threadIdx.x == 0) *flag = (cnt > 64) ? 1 : 0;
}

// ---------- 1. embedding + positional -> bf16 h ----------
__global__ __launch_bounds__(256) void embed_kernel(const int* __restrict__ x,
                                                    const void* __restrict__ ew,
                                                    const void* __restrict__ pos,
                                                    u16* __restrict__ h,
                                                    const int* __restrict__ flagp) {
    const int f = *flagp;
    const int i = blockIdx.x;        // token row 0..MM-1
    const int t = i & (TT - 1);      // position within sequence
    const int row = x[i];
    const int c = threadIdx.x * 4;
    float4 e, p;
    if (f) {
        e = *(const float4*)((const float*)ew + (size_t)row * CC + c);
        p = *(const float4*)((const float*)pos + (size_t)t * CC + c);
    } else {
        ushort4 eu = *(const ushort4*)((const u16*)ew + (size_t)row * CC + c);
        ushort4 pu = *(const ushort4*)((const u16*)pos + (size_t)t * CC + c);
        e = make_float4(bf2f(eu.x), bf2f(eu.y), bf2f(eu.z), bf2f(eu.w));
        p = make_float4(bf2f(pu.x), bf2f(pu.y), bf2f(pu.z), bf2f(pu.w));
    }
    ushort4 o;
    o.x = f2bf(e.x + p.x); o.y = f2bf(e.y + p.y);
    o.z = f2bf(e.z + p.z); o.w = f2bf(e.w + p.w);
    *(ushort4*)&h[(size_t)i * CC + c] = o;
}

// ---------- 2. GEMM: out[m,n] = sum_k A[m,k]*W[n,k] (+bias[n]) (+res[m,n]) ----------
// A bf16 [M,K] (ours). W/bias: dtype per flag, element offsets passed in.
// 128x128 tile, BK=16, 256 threads, 8x8 micro-tile, fp32 FMA.
__global__ __launch_bounds__(256) void gemm_nt(const u16* __restrict__ A,
                                               const void* __restrict__ W, size_t wOff,
                                               void* __restrict__ outP,
                                               const void* __restrict__ bias, size_t bOff,
                                               const u16* __restrict__ res,
                                               int M, int N, int K, int outFlagged,
                                               const int* __restrict__ flagp) {
    const int f = *flagp;
    __shared__ float As[16][128];
    __shared__ float Bs[16][128];
    const int tid = threadIdx.x;
    const int tx = tid & 15;   // 16 col-groups of 8
    const int ty = tid >> 4;   // 16 row-groups of 8
    const int m0 = blockIdx.y * 128, n0 = blockIdx.x * 128;

    const int ar = tid >> 1;          // 0..127 (row within tile)
    const int ak = (tid & 1) * 8;     // k offset 0,8

    float acc[8][8] = {};

    for (int kt = 0; kt < K; kt += 16) {
        uint4 a4 = *(const uint4*)&A[(size_t)(m0 + ar) * K + kt + ak];
        float wv[8];
        if (f) {
            const float* Wf = (const float*)W + wOff;
            *(float4*)&wv[0] = *(const float4*)&Wf[(size_t)(n0 + ar) * K + kt + ak];
            *(float4*)&wv[4] = *(const float4*)&Wf[(size_t)(n0 + ar) * K + kt + ak + 4];
        } else {
            const u16* Wb = (const u16*)W + wOff;
            uint4 w4 = *(const uint4*)&Wb[(size_t)(n0 + ar) * K + kt + ak];
            wv[0] = bf2f((u16)(w4.x & 0xffffu)); wv[1] = bf2f((u16)(w4.x >> 16));
            wv[2] = bf2f((u16)(w4.y & 0xffffu)); wv[3] = bf2f((u16)(w4.y >> 16));
            wv[4] = bf2f((u16)(w4.z & 0xffffu)); wv[5] = bf2f((u16)(w4.z >> 16));
            wv[6] = bf2f((u16)(w4.w & 0xffffu)); wv[7] = bf2f((u16)(w4.w >> 16));
        }
        As[ak + 0][ar] = bf2f((u16)(a4.x & 0xffffu));
        As[ak + 1][ar] = bf2f((u16)(a4.x >> 16));
        As[ak + 2][ar] = bf2f((u16)(a4.y & 0xffffu));
        As[ak + 3][ar] = bf2f((u16)(a4.y >> 16));
        As[ak + 4][ar] = bf2f((u16)(a4.z & 0xffffu));
        As[ak + 5][ar] = bf2f((u16)(a4.z >> 16));
        As[ak + 6][ar] = bf2f((u16)(a4.w & 0xffffu));
        As[ak + 7][ar] = bf2f((u16)(a4.w >> 16));
        Bs[ak + 0][ar] = wv[0]; Bs[ak + 1][ar] = wv[1];
        Bs[ak + 2][ar] = wv[2]; Bs[ak + 3][ar] = wv[3];
        Bs[ak + 4][ar] = wv[4]; Bs[ak + 5][ar] = wv[5];
        Bs[ak + 6][ar] = wv[6]; Bs[ak + 7][ar] = wv[7];
        __syncthreads();
#pragma unroll
        for (int kk = 0; kk < 16; ++kk) {
            float av[8], bv[8];
            *(float4*)&av[0] = *(const float4*)&As[kk][ty * 8];
            *(float4*)&av[4] = *(const float4*)&As[kk][ty * 8 + 4];
            *(float4*)&bv[0] = *(const float4*)&Bs[kk][tx * 8];
            *(float4*)&bv[4] = *(const float4*)&Bs[kk][tx * 8 + 4];
#pragma unroll
            for (int i = 0; i < 8; ++i)
#pragma unroll
                for (int j = 0; j < 8; ++j)
                    acc[i][j] += av[i] * bv[j];
        }
        __syncthreads();
    }

#pragma unroll
    for (int i = 0; i < 8; ++i) {
        const int m = m0 + ty * 8 + i;
#pragma unroll
        for (int j = 0; j < 8; j += 4) {
            const int n = n0 + tx * 8 + j;
            float4 vv = make_float4(acc[i][j], acc[i][j + 1], acc[i][j + 2], acc[i][j + 3]);
            if (bias) {
                if (f) {
                    float4 bb = *(const float4*)((const float*)bias + bOff + n);
                    vv.x += bb.x; vv.y += bb.y; vv.z += bb.z; vv.w += bb.w;
                } else {
                    ushort4 bb = *(const ushort4*)((const u16*)bias + bOff + n);
                    vv.x += bf2f(bb.x); vv.y += bf2f(bb.y);
                    vv.z += bf2f(bb.z); vv.w += bf2f(bb.w);
                }
            }
            if (res) {
                ushort4 rr = *(const ushort4*)&res[(size_t)m * N + n];
                vv.x += bf2f(rr.x); vv.y += bf2f(rr.y);
                vv.z += bf2f(rr.z); vv.w += bf2f(rr.w);
            }
            if (outFlagged && f) {
                *(float4*)((float*)outP + (size_t)m * N + n) = vv;
            } else {
                ushort4 ob;
                ob.x = f2bf(vv.x); ob.y = f2bf(vv.y);
                ob.z = f2bf(vv.z); ob.w = f2bf(vv.w);
                *(ushort4*)((u16*)outP + (size_t)m * N + n) = ob;
            }
        }
    }
}

// ---------- 3. flash attention, split-K: 4 waves share one 64-query tile ----------
// grid = (B*H, T/64) with blockIdx.y REVERSED (heavy q-tiles dispatch first);
// block = 256 threads = 4 waves. lane = query row. Wave w handles 16-row KV
// tiles t with t%4==w -> exactly (qt+1) tiles per wave (lockstep barriers ok).
__global__ __launch_bounds__(256) void flash_attn(const u16* __restrict__ q,
                                                  const u16* __restrict__ k,
                                                  const u16* __restrict__ v,
                                                  u16* __restrict__ ctx) {
    const int bh = blockIdx.x;          // 0..B*H-1
    const int b = bh >> 4;              // /HH
    const int hd = bh & 15;             // %HH
    const int qt = gridDim.y - 1 - blockIdx.y;  // heavy tiles first
    const int qb = qt * 64;
    const int w = threadIdx.x >> 6;     // wave 0..3
    const int lane = threadIdx.x & 63;  // query within tile
    const int qrow = qb + lane;
    const float scale = 0.125f;         // 1/sqrt(64)

    __shared__ float Ks[4][16][64];     // per-wave staging (8KB/wave K+V)
    __shared__ float Vs[4][16][64];
    __shared__ float Macc[64][65];      // merge buffer, +1 pad kills bank conflict
    __shared__ float Mm[64], Ml[64];

    const u16* qp = q + ((size_t)(b * TT + qrow)) * CC + hd * DD;
    float qr[64];
#pragma unroll
    for (int j = 0; j < 64; j += 4) {
        ushort4 t4 = *(const ushort4*)&qp[j];
        qr[j] = bf2f(t4.x); qr[j + 1] = bf2f(t4.y);
        qr[j + 2] = bf2f(t4.z); qr[j + 3] = bf2f(t4.w);
    }
    float acc[64] = {};
    float mx = -1e30f, l = 0.f;

    const int ntiles = (qt + 1) * 4;    // 16-row KV tiles covering [0, qb+64)
    for (int t = w; t < ntiles; t += 4) {
        const int kv0 = t * 16;
        // stage 16x64 K and V into this wave's private buffer
#pragma unroll
        for (int it = 0; it < 4; ++it) {
            const int cidx = it * 64 + lane;    // 0..255
            const int row = cidx >> 4;          // 0..15
            const int c4 = (cidx & 15) * 4;     // 0..60
            const size_t g = ((size_t)(b * TT + kv0 + row)) * CC + hd * DD + c4;
            ushort4 k4 = *(const ushort4*)&k[g];
            ushort4 v4 = *(const ushort4*)&v[g];
            Ks[w][row][c4 + 0] = bf2f(k4.x); Ks[w][row][c4 + 1] = bf2f(k4.y);
            Ks[w][row][c4 + 2] = bf2f(k4.z); Ks[w][row][c4 + 3] = bf2f(k4.w);
            Vs[w][row][c4 + 0] = bf2f(v4.x); Vs[w][row][c4 + 1] = bf2f(v4.y);
            Vs[w][row][c4 + 2] = bf2f(v4.z); Vs[w][row][c4 + 3] = bf2f(v4.w);
        }
        __syncthreads();

        float s[16];
#pragma unroll
        for (int kk = 0; kk < 16; ++kk) {
            float p0 = 0.f, p1 = 0.f, p2 = 0.f, p3 = 0.f;
#pragma unroll
            for (int j = 0; j < 64; j += 4) {
                p0 += qr[j]     * Ks[w][kk][j];
                p1 += qr[j + 1] * Ks[w][kk][j + 1];
                p2 += qr[j + 2] * Ks[w][kk][j + 2];
                p3 += qr[j + 3] * Ks[w][kk][j + 3];
            }
            float sv = ((p0 + p1) + (p2 + p3)) * scale;
            s[kk] = (kv0 + kk <= qrow) ? sv : -1e30f;  // causal mask
        }
        float bm = s[0];
#pragma unroll
        for (int kk = 1; kk < 16; ++kk) bm = fmaxf(bm, s[kk]);
        const float mnew = fmaxf(mx, bm);
        const float corr = __expf(mx - mnew);   // 1.0 if both -1e30 (acc=l=0, harmless)
        l *= corr;
#pragma unroll
        for (int j = 0; j < 64; ++j) acc[j] *= corr;
#pragma unroll
        for (int kk = 0; kk < 16; ++kk) {
            // guard: all-masked tile would give exp(-1e30 - (-1e30)) = 1 -> force 0
            const float p = (s[kk] > -1e29f) ? __expf(s[kk] - mnew) : 0.f;
            l += p;
#pragma unroll
            for (int j = 0; j < 64; j += 4) {
                float4 vv = *(const float4*)&Vs[w][kk][j];   // broadcast read
                acc[j]     += p * vv.x;
                acc[j + 1] += p * vv.y;
                acc[j + 2] += p * vv.z;
                acc[j + 3] += p * vv.w;
            }
        }
        mx = mnew;
        __syncthreads();
    }

    // sequential online-softmax merge: wave src publishes, wave 0 folds in
    for (int src = 1; src < 4; ++src) {
        if (w == src) {
            Mm[lane] = mx; Ml[lane] = l;
#pragma unroll
            for (int j = 0; j < 64; ++j) Macc[lane][j] = acc[j];
        }
        __syncthreads();
        if (w == 0) {
            const float m2 = Mm[lane], l2 = Ml[lane];
            const float mN = fmaxf(mx, m2);
            const float e1 = __expf(mx - mN);
            const float e2 = __expf(m2 - mN);   // 0 if src strip was empty (m2=-1e30)
            l = l * e1 + l2 * e2;
#pragma unroll
            for (int j = 0; j < 64; ++j) acc[j] = acc[j] * e1 + Macc[lane][j] * e2;
            mx = mN;
        }
        __syncthreads();
    }

    if (w == 0) {
        const float inv = 1.0f / l;   // l>0: KV row 0 is always unmasked (wave 0, tile 0)
        u16* cp = ctx + ((size_t)(b * TT + qrow)) * CC + hd * DD;
#pragma unroll
        for (int j = 0; j < 64; j += 4) {
            ushort4 o;
            o.x = f2bf(acc[j] * inv); o.y = f2bf(acc[j + 1] * inv);
            o.z = f2bf(acc[j + 2] * inv); o.w = f2bf(acc[j + 3] * inv);
            *(ushort4*)&cp[j] = o;
        }
    }
}

// ---------- 4. d2d copy (h -> scratch), 16B per thread ----------
__global__ __launch_bounds__(256) void copy16_kernel(const uint4* __restrict__ src,
                                                     uint4* __restrict__ dst) {
    const size_t i = (size_t)blockIdx.x * 256 + threadIdx.x;
    dst[i] = src[i];
}

// ---------- 5. loss: per-row logsumexp + NLL ----------
__global__ __launch_bounds__(256) void loss_row(const void* __restrict__ logits,
                                                const int* __restrict__ target,
                                                float* __restrict__ nll,
                                                const int* __restrict__ flagp) {
    const int f = *flagp;
    const int r = blockIdx.x;
    __shared__ float red[4];
    const float* lpf = (const float*)logits + (size_t)r * VV;
    const u16*   lpb = (const u16*)logits + (size_t)r * VV;

    float lmax = -1e30f;
    if (f) { for (int i = threadIdx.x; i < VV; i += 256) lmax = fmaxf(lmax, lpf[i]); }
    else   { for (int i = threadIdx.x; i < VV; i += 256) lmax = fmaxf(lmax, bf2f(lpb[i])); }
#pragma unroll
    for (int off = 32; off > 0; off >>= 1) lmax = fmaxf(lmax, __shfl_down(lmax, off, 64));
    const int wid = threadIdx.x >> 6, lid = threadIdx.x & 63;
    if (lid == 0) red[wid] = lmax;
    __syncthreads();
    lmax = fmaxf(fmaxf(red[0], red[1]), fmaxf(red[2], red[3]));

    float sum = 0.f;
    if (f) { for (int i = threadIdx.x; i < VV; i += 256) sum += __expf(lpf[i] - lmax); }
    else   { for (int i = threadIdx.x; i < VV; i += 256) sum += __expf(bf2f(lpb[i]) - lmax); }
#pragma unroll
    for (int off = 32; off > 0; off >>= 1) sum += __shfl_down(sum, off, 64);
    __syncthreads();
    if (lid == 0) red[wid] = sum;
    __syncthreads();
    if (threadIdx.x == 0) {
        const float s = red[0] + red[1] + red[2] + red[3];
        const float tl = f ? lpf[target[r]] : bf2f(lpb[target[r]]);
        nll[r] = lmax + __logf(s) - tl;   // = -(log_softmax at target)
    }
}

__global__ __launch_bounds__(256) void loss_final(const float* __restrict__ nll,
                                                  void* __restrict__ out,
                                                  const int* __restrict__ flagp) {
    __shared__ float red[4];
    float s = 0.f;
    for (int i = threadIdx.x; i < MM; i += 256) s += nll[i];
#pragma unroll
    for (int off = 32; off > 0; off >>= 1) s += __shfl_down(s, off, 64);
    if ((threadIdx.x & 63) == 0) red[threadIdx.x >> 6] = s;
    __syncthreads();
    if (threadIdx.x == 0) {
        const float t = (red[0] + red[1] + red[2] + red[3]) / (float)MM;
        if (*flagp) ((float*)out)[(size_t)MM * VV] = t;
        else        ((u16*)out)[(size_t)MM * VV] = f2bf(t);
    }
}

// ---------- launch ----------
extern "C" void kernel_launch(void* const* d_in, const int* in_sizes, int n_in,
                              void* d_out, int out_size, void* d_ws, size_t ws_size,
                              hipStream_t stream) {
    const int* x      = (const int*)d_in[0];
    const int* target = (const int*)d_in[1];
    const void* ew  = d_in[2];
    const void* pos = d_in[3];
    const void* Wq  = d_in[4];
    const void* bq  = d_in[5];
    const void* Wk  = d_in[6];
    const void* bk  = d_in[7];
    const void* Wv  = d_in[8];
    const void* bv  = d_in[9];
    const void* Wo  = d_in[10];
    const void* bo  = d_in[11];
    const void* Wu  = d_in[12];

    int* flagp = (int*)d_ws;   // 4 bytes of workspace: dtype flag

    // bf16 scratch inside d_out (dead until logits GEMM; >=64 MiB both modes):
    u16* outw = (u16*)d_out;
    u16* hB  = outw;
    u16* qB  = outw + (size_t)1 * MM * CC;
    u16* kB  = outw + (size_t)2 * MM * CC;
    u16* vB  = outw + (size_t)3 * MM * CC;
    u16* ctx = qB;  // flash block writes exactly the (row, head-slice) it read
    // Scratch inside the consumed embed_w buffer (>=16 MiB both modes):
    u16* hScr  = (u16*)ew;                                   // [0, 8M) bytes
    float* nll = (float*)((char*)ew + 12u * 1024 * 1024);    // [12M, 12M+16K)

    probe_kernel<<<1, 256, 0, stream>>>((const u16*)Wu, flagp);
    embed_kernel<<<MM, 256, 0, stream>>>(x, ew, pos, hB, flagp);  // last read of ew

    const dim3 gP(CC / 128, MM / 128);   // projection GEMMs: 8 x 32 blocks
    for (int l = 0; l < LL; ++l) {
        const size_t wOff = (size_t)l * CC * CC, bOff = (size_t)l * CC;
        gemm_nt<<<gP, 256, 0, stream>>>(hB, Wq, wOff, qB, bq, bOff, nullptr, MM, CC, CC, 0, flagp);
        gemm_nt<<<gP, 256, 0, stream>>>(hB, Wk, wOff, kB, bk, bOff, nullptr, MM, CC, CC, 0, flagp);
        gemm_nt<<<gP, 256, 0, stream>>>(hB, Wv, wOff, vB, bv, bOff, nullptr, MM, CC, CC, 0, flagp);
        flash_attn<<<dim3(BB * HH, TT / 64), 256, 0, stream>>>(qB, kB, vB, ctx);
        // out-proj + residual, in-place into hB (res read/write at identical (m,n))
        gemm_nt<<<gP, 256, 0, stream>>>(ctx, Wo, wOff, hB, bo, bOff, hB, MM, CC, CC, 0, flagp);
    }

    // move h out of d_out, then logits GEMM overwrites d_out (dtype per flag)
    copy16_kernel<<<(MM * CC * 2 / 16) / 256, 256, 0, stream>>>((const uint4*)hB, (uint4*)hScr);
    gemm_nt<<<dim3(VV / 128, MM / 128), 256, 0, stream>>>(hScr, Wu, 0, d_out,
                                                          nullptr, 0, nullptr, MM, VV, CC, 1, flagp);
    loss_row<<<MM, 256, 0, stream>>>(d_out, target, nll, flagp);
    loss_final<<<1, 256, 0, stream>>>(nll, d_out, flagp);
}